// Round 17
// baseline (70.679 us; speedup 1.0000x reference)
//
#include <hip/hip_runtime.h>
#include <hip/hip_bf16.h>

// ContrastiveLoss: loss = ( sum_{same & sim<1} (1-sim) + sum_{diff & sim>0.5} sim ) / n
// sim = E E^T, n=8192, d=512. int8 MFMA (mfma_i32_16x16x64_i8), exact i32
// accumulation, quant scale 24, dequant 1/576.
// R17: persistent multi-tile blocks. grid=512 (2 blocks/CU); block (xcd=bid&7,
// slot=bid>>3) owns tiles t = xcd*260 + slot + 64k, k<ntile (slot<4 -> 5 else 4).
// ONE flat window pipeline across all its tiles: ring-3 LDS + counted vmcnt(4)
// continue across tile boundaries (no per-tile fill/drain); stage pointers
// advance at phase 5; epilogue at phase 7 is sync-free (per-lane running sum
// across tiles, weights folded); one cross-wave reduce + one partial per BLOCK
// at kernel end. Label-load waits inside the epilogue self-drain before the
// next window's vmcnt(4) (in-order vmcnt retirement), preserving the counted
// invariant. Window body, swizzle, decode, epilogue math identical to R16.

typedef int i32x4 __attribute__((ext_vector_type(4)));

#define N_EMB 8192
#define D_EMB 512
#define BM    128
#define HKB   64                  // K-bytes per window
#define NPH   8                   // windows per tile
#define TILES 64
#define NBLK  2080                // upper-tri 128^2 tiles
#define PERX  (NBLK / 8)          // 260 tiles per XCD
#define GRID  512                 // 2 blocks/CU
#define MARGIN_F 0.5f
#define QSCALE 24.0f
#define DEQ    (1.0f / (QSCALE * QSCALE))
#define HBYT  (BM * HKB)          // 8 KB per operand half-buffer

__device__ __forceinline__ void gll16(const void* g, void* l) {
    __builtin_amdgcn_global_load_lds(
        (const __attribute__((address_space(1))) void*)g,
        (__attribute__((address_space(3))) void*)l,
        16 /*bytes*/, 0 /*offset*/, 0 /*aux*/);
}

__device__ __forceinline__ void decode_tile(int t, int& tr, int& tc) {
    int r = (int)(64.5f - sqrtf(4160.25f - 2.0f * (float)t));
    while ((r + 1) * TILES - ((r + 1) * r) / 2 <= t) ++r;
    while (r * TILES - (r * (r - 1)) / 2 > t) --r;
    tr = r;
    tc = r + (t - (r * TILES - (r * (r - 1)) / 2));
}

// fp32 -> int8 (scale 24, clamp +-127). 16 floats -> 16 bytes per thread.
__global__ __launch_bounds__(256) void quant_kernel(const float* __restrict__ in,
                                                    int4* __restrict__ out, int n16) {
    int i = blockIdx.x * blockDim.x + threadIdx.x;
    if (i >= n16) return;
    const float4* p = reinterpret_cast<const float4*>(in) + i * 4;
    int4 o;
    int* po = reinterpret_cast<int*>(&o);
#pragma unroll
    for (int j = 0; j < 4; ++j) {
        float4 v = p[j];
        int b0 = (int)rintf(fminf(fmaxf(v.x * QSCALE, -127.f), 127.f));
        int b1 = (int)rintf(fminf(fmaxf(v.y * QSCALE, -127.f), 127.f));
        int b2 = (int)rintf(fminf(fmaxf(v.z * QSCALE, -127.f), 127.f));
        int b3 = (int)rintf(fminf(fmaxf(v.w * QSCALE, -127.f), 127.f));
        po[j] = (b0 & 255) | ((b1 & 255) << 8) | ((b2 & 255) << 16) | ((b3 & 255) << 24);
    }
    out[i] = o;
}

__global__ __launch_bounds__(256) void loss_kernel(const char* __restrict__ E8,
                                                   const int* __restrict__ label,
                                                   float* __restrict__ partials) {
    const int bid  = blockIdx.x;
    const int xcd  = bid & 7, slot = bid >> 3;       // slot 0..63
    const int ntile = (slot < (PERX - 4 * 64)) ? 5 : 4;  // 260 = 4*64 + 4
    const int W = ntile * NPH;

    __shared__ char  lds[3][2][HBYT];   // ring-3: [A 8KB | B 8KB] x 3 = 48 KB
    __shared__ float red[4];

    const int tid  = threadIdx.x;
    const int wid  = tid >> 6, lane = tid & 63;
    const int wrow = wid >> 1, wcol = wid & 1;   // 2x2 waves, each 64x64 out
    const int fr   = lane & 15;
    const int kq   = lane >> 4;

    // staging maps (identical to R16): phys chunk c of row r holds LOGICAL
    // chunk c ^ (r&3); inverse swizzle on global source, lane-linear dest.
    const int sw = (((tid & 3) ^ ((tid >> 2) & 3)) << 4);
    const int r0 = tid >> 2, r1 = 64 + (tid >> 2);
    const int d0 = tid << 4, d1 = (tid + 256) << 4;
    const int psw = ((kq ^ (fr & 3)) << 4);      // ds_read chunk swizzle

    // first tile (read side == stage side initially)
    int rd_t = xcd * PERX + slot;
    int tr, tc;
    decode_tile(rd_t, tr, tc);
    int rd_row0 = tr * BM, rd_col0 = tc * BM;
    int nx_row0 = rd_row0, nx_col0 = rd_col0;

    // stage-side pointers (advance at phase 5 of each tile)
    const char* gA0 = E8 + (size_t)(rd_row0 + r0) * D_EMB + sw;
    const char* gA1 = E8 + (size_t)(rd_row0 + r1) * D_EMB + sw;
    const char* gB0 = E8 + (size_t)(rd_col0 + r0) * D_EMB + sw;
    const char* gB1 = E8 + (size_t)(rd_col0 + r1) * D_EMB + sw;

    i32x4 acc[4][4] = {};
    float lane_sum = 0.f;      // running masked sum across this block's tiles

    // prologue: stage windows 0 and 1 (8 glls outstanding)
    gll16(gA0,       &lds[0][0][d0]); gll16(gA1,       &lds[0][0][d1]);
    gll16(gB0,       &lds[0][1][d0]); gll16(gB1,       &lds[0][1][d1]);
    gll16(gA0 + HKB, &lds[1][0][d0]); gll16(gA1 + HKB, &lds[1][0][d1]);
    gll16(gB0 + HKB, &lds[1][1][d0]); gll16(gB1 + HKB, &lds[1][1][d1]);

    int ktile = 0;
#pragma unroll 1
    for (int w = 0; w < W; ++w) {
        const int rg = w % 3;
        // counted wait: all but the newest 4 glls done = window w landed.
        if (w < W - 1) {
            asm volatile("s_waitcnt vmcnt(4)" ::: "memory");
        } else {
            asm volatile("s_waitcnt vmcnt(0)" ::: "memory");
        }
        __builtin_amdgcn_s_barrier();   // publish window w; ring (w+2)%3 free

        // stage window w+2 (crosses tile boundaries seamlessly)
        if (w + 2 < W) {
            const int rg2 = (w + 2) % 3;
            const int ko  = ((w + 2) & 7) * HKB;
            gll16(gA0 + ko, &lds[rg2][0][d0]); gll16(gA1 + ko, &lds[rg2][0][d1]);
            gll16(gB0 + ko, &lds[rg2][1][d0]); gll16(gB1 + ko, &lds[rg2][1][d1]);
        }

        // read window w's fragments and MFMA
        i32x4 a[4], b[4];
#pragma unroll
        for (int m = 0; m < 4; ++m)
            a[m] = *reinterpret_cast<const i32x4*>(
                &lds[rg][0][((wrow * 64 + m * 16 + fr) << 6) + psw]);
#pragma unroll
        for (int n = 0; n < 4; ++n)
            b[n] = *reinterpret_cast<const i32x4*>(
                &lds[rg][1][((wcol * 64 + n * 16 + fr) << 6) + psw]);
        asm volatile("s_waitcnt lgkmcnt(0)" ::: "memory");
        __builtin_amdgcn_sched_barrier(0);   // rule #18
        __builtin_amdgcn_s_setprio(1);
#pragma unroll
        for (int m = 0; m < 4; ++m)
#pragma unroll
            for (int n = 0; n < 4; ++n)
                acc[m][n] = __builtin_amdgcn_mfma_i32_16x16x64_i8(a[m], b[n], acc[m][n], 0, 0, 0);
        __builtin_amdgcn_s_setprio(0);

        const int ph = w & 7;
        if (ph == 5 && ktile + 1 < ntile) {
            // advance stage side to next tile (used from window w+1's stage of
            // local phase 0, i.e. w+3... issued at w+1 staging (w+3)&7=0) —
            // ready one window early by construction.
            int tn = rd_t + 64;
            int tr2, tc2;
            decode_tile(tn, tr2, tc2);
            nx_row0 = tr2 * BM; nx_col0 = tc2 * BM;
            gA0 = E8 + (size_t)(nx_row0 + r0) * D_EMB + sw;
            gA1 = E8 + (size_t)(nx_row0 + r1) * D_EMB + sw;
            gB0 = E8 + (size_t)(nx_col0 + r0) * D_EMB + sw;
            gB1 = E8 + (size_t)(nx_col0 + r1) * D_EMB + sw;
        }
        if (ph == 7) {
            // sync-free epilogue for tile rd_t: per-lane masked sum.
            // C/D layout col = lane&15, row = (lane>>4)*4 + reg.
            float local = 0.f;
            int lj[4];
#pragma unroll
            for (int n = 0; n < 4; ++n)
                lj[n] = label[rd_col0 + wcol * 64 + n * 16 + fr];
            const int rb = kq << 2;
#pragma unroll
            for (int m = 0; m < 4; ++m) {
#pragma unroll
                for (int r = 0; r < 4; ++r) {
                    const int li = label[rd_row0 + wrow * 64 + m * 16 + rb + r];
#pragma unroll
                    for (int n = 0; n < 4; ++n) {
                        const float s = (float)acc[m][n][r] * DEQ;
                        if (li == lj[n]) {
                            if (s < 1.0f) local += 1.0f - s;
                        } else if (s > MARGIN_F) {
                            local += s;
                        }
                    }
                }
            }
            lane_sum += (rd_row0 != rd_col0) ? 2.0f * local : local;
            // note: diagonal tiles keep weight 1 (self-pairs contribute 0)
#pragma unroll
            for (int m = 0; m < 4; ++m)
#pragma unroll
                for (int n = 0; n < 4; ++n)
                    acc[m][n] = i32x4{0, 0, 0, 0};
            rd_t += 64; rd_row0 = nx_row0; rd_col0 = nx_col0;
            ++ktile;
        }
    }

    // one cross-wave reduce + one partial per block
#pragma unroll
    for (int off = 32; off > 0; off >>= 1) lane_sum += __shfl_xor(lane_sum, off);
    if (lane == 0) red[wid] = lane_sum;
    __syncthreads();
    if (tid == 0) partials[bid] = red[0] + red[1] + red[2] + red[3];
}

__global__ __launch_bounds__(256) void reduce_kernel(const float* __restrict__ partials,
                                                     float* __restrict__ out, int nb) {
    float s = 0.f;
    for (int i = threadIdx.x; i < nb; i += 256) s += partials[i];
#pragma unroll
    for (int off = 32; off > 0; off >>= 1) s += __shfl_xor(s, off);
    __shared__ float red[4];
    if ((threadIdx.x & 63) == 0) red[threadIdx.x >> 6] = s;
    __syncthreads();
    if (threadIdx.x == 0) {
        out[0] = (red[0] + red[1] + red[2] + red[3]) * (1.0f / (float)N_EMB);
        out[1] = 0.f;
        out[2] = 0.f;
    }
}

extern "C" void kernel_launch(void* const* d_in, const int* in_sizes, int n_in,
                              void* d_out, int out_size, void* d_ws, size_t ws_size,
                              hipStream_t stream) {
    const float* emb   = (const float*)d_in[0];
    const int*   label = (const int*)d_in[1];
    float*       out   = (float*)d_out;

    char*  E8      = (char*)d_ws;                                   // 4 MB
    float* partial = (float*)((char*)d_ws + (size_t)N_EMB * D_EMB); // 2 KB

    const int n16 = N_EMB * D_EMB / 16;
    quant_kernel<<<(n16 + 255) / 256, 256, 0, stream>>>(emb, (int4*)E8, n16);

    loss_kernel<<<GRID, 256, 0, stream>>>(E8, label, partial);

    reduce_kernel<<<1, 256, 0, stream>>>(partial, out, GRID);
}

// Round 18
// 42.841 us; speedup vs baseline: 1.6498x; 1.6498x over previous
//
#include <hip/hip_runtime.h>
#include <hip/hip_bf16.h>

// ContrastiveLoss: loss = ( sum_{same & sim<1} (1-sim) + sum_{diff & sim>0.5} sim ) / n
// sim = E E^T, n=8192, d=512. int8 MFMA (mfma_i32_16x16x64_i8), exact i32
// accumulation, quant scale 24, dequant 1/576.
// R18 = R16's exact window structure (ring-3 LDS, HKB=64, counted vmcnt,
// ONE barrier/window, chunk^(row&3) swizzle, T1, triangular grid) at
// 8 WAVES (512 threads, 2x4 of 64x32 wave tiles, acc[4][2]=32 AGPR).
// Rationale: all i8 rounds ran ~8-9 waves/CU (136 regs -> 3/SIMD) and idled
// ~50% on latency; 64x32 tiles cut regs to ~88 -> 4-5 waves/SIMD -> ~16
// waves/CU. Per-thread glls/window = 2 -> counted wait is vmcnt(2).

typedef int i32x4 __attribute__((ext_vector_type(4)));

#define N_EMB 8192
#define D_EMB 512
#define BM    128
#define HKB   64                 // K-bytes per window
#define NPH   (D_EMB / HKB)      // 8 windows
#define TILES (N_EMB / BM)       // 64
#define NBLK  (TILES * (TILES + 1) / 2)   // 2080
#define MARGIN_F 0.5f
#define QSCALE 24.0f
#define DEQ    (1.0f / (QSCALE * QSCALE))  // 1/576
#define HBYT  (BM * HKB)         // 8192 B per operand half-buffer

__device__ __forceinline__ void gll16(const void* g, void* l) {
    __builtin_amdgcn_global_load_lds(
        (const __attribute__((address_space(1))) void*)g,
        (__attribute__((address_space(3))) void*)l,
        16 /*bytes*/, 0 /*offset*/, 0 /*aux*/);
}

// fp32 -> int8 (scale 24, clamp +-127). 16 floats -> 16 bytes per thread.
__global__ __launch_bounds__(256) void quant_kernel(const float* __restrict__ in,
                                                    int4* __restrict__ out, int n16) {
    int i = blockIdx.x * blockDim.x + threadIdx.x;
    if (i >= n16) return;
    const float4* p = reinterpret_cast<const float4*>(in) + i * 4;
    int4 o;
    int* po = reinterpret_cast<int*>(&o);
#pragma unroll
    for (int j = 0; j < 4; ++j) {
        float4 v = p[j];
        int b0 = (int)rintf(fminf(fmaxf(v.x * QSCALE, -127.f), 127.f));
        int b1 = (int)rintf(fminf(fmaxf(v.y * QSCALE, -127.f), 127.f));
        int b2 = (int)rintf(fminf(fmaxf(v.z * QSCALE, -127.f), 127.f));
        int b3 = (int)rintf(fminf(fmaxf(v.w * QSCALE, -127.f), 127.f));
        po[j] = (b0 & 255) | ((b1 & 255) << 8) | ((b2 & 255) << 16) | ((b3 & 255) << 24);
    }
    out[i] = o;
}

__global__ __launch_bounds__(512) void loss_kernel(const char* __restrict__ E8,
                                                   const int* __restrict__ label,
                                                   float* __restrict__ partials) {
    // T1: XCD-contiguous logical tile index (2080 % 8 == 0)
    const int bid = blockIdx.x;
    const int t = (bid & 7) * (NBLK / 8) + (bid >> 3);

    // triangular decode: t -> (tr, tc), tr <= tc (validated R2..R16)
    int tr = (int)(64.5f - sqrtf(4160.25f - 2.0f * (float)t));
    while ((tr + 1) * TILES - ((tr + 1) * tr) / 2 <= t) ++tr;
    while (tr * TILES - (tr * (tr - 1)) / 2 > t) --tr;
    const int tc = tr + (t - (tr * TILES - (tr * (tr - 1)) / 2));

    __shared__ char  lds[3][2][HBYT];   // ring-3: [A 8KB | B 8KB] x 3 = 48 KB
    __shared__ float red[8];

    const int tid  = threadIdx.x;
    const int wid  = tid >> 6, lane = tid & 63;
    const int wrow = wid >> 2, wcol = wid & 3;   // 2x4 waves, each 64x32 out
    const int fr   = lane & 15;                  // fragment row(A)/row(B)/col(C)
    const int kq   = lane >> 4;                  // k-16B-chunk 0..3
    const int row0 = tr * BM, col0 = tc * BM;

    // staging: per half = 128 rows x 64 B = 512 x 16B slots; thread covers
    // slot tid of each operand (512 threads). Phys chunk c of row r holds
    // LOGICAL chunk c ^ (r&3): inverse swizzle on global source, lane-linear
    // LDS dest (wave-uniform base + lane*16B holds per wave).
    const int sw = (((tid & 3) ^ ((tid >> 2) & 3)) << 4);
    const int r0 = tid >> 2;
    const char* gA0 = E8 + (size_t)(row0 + r0) * D_EMB + sw;
    const char* gB0 = E8 + (size_t)(col0 + r0) * D_EMB + sw;
    const int d0 = tid << 4;

    i32x4 acc[4][2] = {};

    // ds_read phys chunk: kq ^ (row&3); row&3 == fr&3 for all fragment rows.
    const int psw = ((kq ^ (fr & 3)) << 4);

    // prologue: stage windows 0 and 1 (4 glls outstanding per thread: 2+2)
    gll16(gA0,       &lds[0][0][d0]); gll16(gB0,       &lds[0][1][d0]);
    gll16(gA0 + HKB, &lds[1][0][d0]); gll16(gB0 + HKB, &lds[1][1][d0]);

#pragma unroll
    for (int p = 0; p < NPH; ++p) {
        const int rg = p % 3;
        // counted wait: all but newest 2 glls done = window p landed;
        // window p+1's 2 stay in flight. Final window drains.
        if (p < NPH - 1) {
            asm volatile("s_waitcnt vmcnt(2)" ::: "memory");
        } else {
            asm volatile("s_waitcnt vmcnt(0)" ::: "memory");
        }
        __builtin_amdgcn_s_barrier();   // publish window p; ring (p+2)%3 free

        // stage window p+2 (its last readers retired before this barrier)
        if (p + 2 < NPH) {
            const int rg2 = (p + 2) % 3;
            const int ko  = (p + 2) * HKB;
            gll16(gA0 + ko, &lds[rg2][0][d0]);
            gll16(gB0 + ko, &lds[rg2][1][d0]);
        }

        // read this window's fragments and MFMA
        i32x4 a[4], b[2];
#pragma unroll
        for (int m = 0; m < 4; ++m)
            a[m] = *reinterpret_cast<const i32x4*>(
                &lds[rg][0][((wrow * 64 + m * 16 + fr) << 6) + psw]);
#pragma unroll
        for (int n = 0; n < 2; ++n)
            b[n] = *reinterpret_cast<const i32x4*>(
                &lds[rg][1][((wcol * 32 + n * 16 + fr) << 6) + psw]);
        asm volatile("s_waitcnt lgkmcnt(0)" ::: "memory");
        __builtin_amdgcn_sched_barrier(0);   // rule #18
        __builtin_amdgcn_s_setprio(1);
#pragma unroll
        for (int m = 0; m < 4; ++m)
#pragma unroll
            for (int n = 0; n < 2; ++n)
                acc[m][n] = __builtin_amdgcn_mfma_i32_16x16x64_i8(a[m], b[n], acc[m][n], 0, 0, 0);
        __builtin_amdgcn_s_setprio(0);
    }

    // ---- epilogue: C/D layout col = lane&15, row = (lane>>4)*4 + reg.
    float local = 0.f;
    int lj[2];
#pragma unroll
    for (int n = 0; n < 2; ++n) lj[n] = label[col0 + wcol * 32 + n * 16 + fr];
    const int rb = kq << 2;
#pragma unroll
    for (int m = 0; m < 4; ++m) {
#pragma unroll
        for (int r = 0; r < 4; ++r) {
            const int li = label[row0 + wrow * 64 + m * 16 + rb + r];
#pragma unroll
            for (int n = 0; n < 2; ++n) {
                const float s = (float)acc[m][n][r] * DEQ;
                if (li == lj[n]) {
                    if (s < 1.0f) local += 1.0f - s;
                } else if (s > MARGIN_F) {
                    local += s;
                }
            }
        }
    }
    if (tr != tc) local *= 2.0f;   // off-diag tile stands for (i,j) and (j,i)

#pragma unroll
    for (int off = 32; off > 0; off >>= 1) local += __shfl_xor(local, off);
    if (lane == 0) red[wid] = local;
    __syncthreads();
    if (tid == 0) {
        float s = 0.f;
#pragma unroll
        for (int i = 0; i < 8; ++i) s += red[i];
        partials[t] = s;
    }
}

__global__ __launch_bounds__(256) void reduce_kernel(const float* __restrict__ partials,
                                                     float* __restrict__ out, int nb) {
    float s = 0.f;
    for (int i = threadIdx.x; i < nb; i += 256) s += partials[i];
#pragma unroll
    for (int off = 32; off > 0; off >>= 1) s += __shfl_xor(s, off);
    __shared__ float red[4];
    if ((threadIdx.x & 63) == 0) red[threadIdx.x >> 6] = s;
    __syncthreads();
    if (threadIdx.x == 0) {
        out[0] = (red[0] + red[1] + red[2] + red[3]) * (1.0f / (float)N_EMB);
        out[1] = 0.f;
        out[2] = 0.f;
    }
}

extern "C" void kernel_launch(void* const* d_in, const int* in_sizes, int n_in,
                              void* d_out, int out_size, void* d_ws, size_t ws_size,
                              hipStream_t stream) {
    const float* emb   = (const float*)d_in[0];
    const int*   label = (const int*)d_in[1];
    float*       out   = (float*)d_out;

    char*  E8      = (char*)d_ws;                                   // 4 MB
    float* partial = (float*)((char*)d_ws + (size_t)N_EMB * D_EMB); // 8.3 KB

    const int n16 = N_EMB * D_EMB / 16;
    quant_kernel<<<(n16 + 255) / 256, 256, 0, stream>>>(emb, (int4*)E8, n16);

    loss_kernel<<<NBLK, 512, 0, stream>>>(E8, label, partial);

    reduce_kernel<<<1, 256, 0, stream>>>(partial, out, NBLK);
}

// Round 19
// 42.539 us; speedup vs baseline: 1.6615x; 1.0071x over previous
//
#include <hip/hip_runtime.h>
#include <hip/hip_bf16.h>

// ContrastiveLoss: loss = ( sum_{same & sim<1} (1-sim) + sum_{diff & sim>0.5} sim ) / n
// sim = E E^T, n=8192, d=512. int8 MFMA (mfma_i32_16x16x64_i8), exact i32
// accumulation, quant scale 24, dequant 1/576.
// R19 = R18 (8 waves of 64x32, ring-3 LDS, counted vmcnt(2), one barrier per
// window, chunk^(row&3) swizzle, T1, triangular grid) with the window interior
// UNPINNED: drop the manual lgkmcnt(0)+sched_barrier before the MFMA cluster
// (rule #18 applies only to inline-asm ds_reads; ours are ordinary loads, so
// the compiler emits fine-grained counted lgkmcnt and interleaves MFMA with
// outstanding reads). ds_reads issue BEFORE the stage glls (reads are on the
// critical path; glls have 2 windows of slack). A sched_barrier(0) directly
// after the publish barrier stops reads hoisting above it.

typedef int i32x4 __attribute__((ext_vector_type(4)));

#define N_EMB 8192
#define D_EMB 512
#define BM    128
#define HKB   64                 // K-bytes per window
#define NPH   (D_EMB / HKB)      // 8 windows
#define TILES (N_EMB / BM)       // 64
#define NBLK  (TILES * (TILES + 1) / 2)   // 2080
#define MARGIN_F 0.5f
#define QSCALE 24.0f
#define DEQ    (1.0f / (QSCALE * QSCALE))  // 1/576
#define HBYT  (BM * HKB)         // 8192 B per operand half-buffer

__device__ __forceinline__ void gll16(const void* g, void* l) {
    __builtin_amdgcn_global_load_lds(
        (const __attribute__((address_space(1))) void*)g,
        (__attribute__((address_space(3))) void*)l,
        16 /*bytes*/, 0 /*offset*/, 0 /*aux*/);
}

// fp32 -> int8 (scale 24, clamp +-127). 16 floats -> 16 bytes per thread.
__global__ __launch_bounds__(256) void quant_kernel(const float* __restrict__ in,
                                                    int4* __restrict__ out, int n16) {
    int i = blockIdx.x * blockDim.x + threadIdx.x;
    if (i >= n16) return;
    const float4* p = reinterpret_cast<const float4*>(in) + i * 4;
    int4 o;
    int* po = reinterpret_cast<int*>(&o);
#pragma unroll
    for (int j = 0; j < 4; ++j) {
        float4 v = p[j];
        int b0 = (int)rintf(fminf(fmaxf(v.x * QSCALE, -127.f), 127.f));
        int b1 = (int)rintf(fminf(fmaxf(v.y * QSCALE, -127.f), 127.f));
        int b2 = (int)rintf(fminf(fmaxf(v.z * QSCALE, -127.f), 127.f));
        int b3 = (int)rintf(fminf(fmaxf(v.w * QSCALE, -127.f), 127.f));
        po[j] = (b0 & 255) | ((b1 & 255) << 8) | ((b2 & 255) << 16) | ((b3 & 255) << 24);
    }
    out[i] = o;
}

__global__ __launch_bounds__(512) void loss_kernel(const char* __restrict__ E8,
                                                   const int* __restrict__ label,
                                                   float* __restrict__ partials) {
    // T1: XCD-contiguous logical tile index (2080 % 8 == 0)
    const int bid = blockIdx.x;
    const int t = (bid & 7) * (NBLK / 8) + (bid >> 3);

    // triangular decode: t -> (tr, tc), tr <= tc (validated R2..R18)
    int tr = (int)(64.5f - sqrtf(4160.25f - 2.0f * (float)t));
    while ((tr + 1) * TILES - ((tr + 1) * tr) / 2 <= t) ++tr;
    while (tr * TILES - (tr * (tr - 1)) / 2 > t) --tr;
    const int tc = tr + (t - (tr * TILES - (tr * (tr - 1)) / 2));

    __shared__ char  lds[3][2][HBYT];   // ring-3: [A 8KB | B 8KB] x 3 = 48 KB
    __shared__ float red[8];

    const int tid  = threadIdx.x;
    const int wid  = tid >> 6, lane = tid & 63;
    const int wrow = wid >> 2, wcol = wid & 3;   // 2x4 waves, each 64x32 out
    const int fr   = lane & 15;                  // fragment row(A)/row(B)/col(C)
    const int kq   = lane >> 4;                  // k-16B-chunk 0..3
    const int row0 = tr * BM, col0 = tc * BM;

    // staging: per half = 128 rows x 64 B = 512 x 16B slots; thread covers
    // slot tid of each operand (512 threads). Phys chunk c of row r holds
    // LOGICAL chunk c ^ (r&3): inverse swizzle on global source, lane-linear
    // LDS dest (wave-uniform base + lane*16B holds per wave).
    const int sw = (((tid & 3) ^ ((tid >> 2) & 3)) << 4);
    const int r0 = tid >> 2;
    const char* gA0 = E8 + (size_t)(row0 + r0) * D_EMB + sw;
    const char* gB0 = E8 + (size_t)(col0 + r0) * D_EMB + sw;
    const int d0 = tid << 4;

    i32x4 acc[4][2] = {};

    // ds_read phys chunk: kq ^ (row&3); row&3 == fr&3 for all fragment rows.
    const int psw = ((kq ^ (fr & 3)) << 4);

    // prologue: stage windows 0 and 1 (4 glls outstanding per thread)
    gll16(gA0,       &lds[0][0][d0]); gll16(gB0,       &lds[0][1][d0]);
    gll16(gA0 + HKB, &lds[1][0][d0]); gll16(gB0 + HKB, &lds[1][1][d0]);

#pragma unroll
    for (int p = 0; p < NPH; ++p) {
        const int rg = p % 3;
        // counted wait: all but newest 2 glls done = window p landed;
        // window p+1's 2 stay in flight. Final window drains.
        if (p < NPH - 1) {
            asm volatile("s_waitcnt vmcnt(2)" ::: "memory");
        } else {
            asm volatile("s_waitcnt vmcnt(0)" ::: "memory");
        }
        __builtin_amdgcn_s_barrier();        // publish window p; ring (p+2)%3 free
        __builtin_amdgcn_sched_barrier(0);   // reads must not hoist above barrier

        // critical path first: this window's fragment reads (ordinary loads;
        // compiler emits fine-grained counted lgkmcnt before each MFMA use)
        i32x4 a[4], b[2];
#pragma unroll
        for (int m = 0; m < 4; ++m)
            a[m] = *reinterpret_cast<const i32x4*>(
                &lds[rg][0][((wrow * 64 + m * 16 + fr) << 6) + psw]);
#pragma unroll
        for (int n = 0; n < 2; ++n)
            b[n] = *reinterpret_cast<const i32x4*>(
                &lds[rg][1][((wcol * 32 + n * 16 + fr) << 6) + psw]);

        // stage window p+2 (2 windows of slack; last readers retired above)
        if (p + 2 < NPH) {
            const int rg2 = (p + 2) % 3;
            const int ko  = (p + 2) * HKB;
            gll16(gA0 + ko, &lds[rg2][0][d0]);
            gll16(gB0 + ko, &lds[rg2][1][d0]);
        }

        __builtin_amdgcn_s_setprio(1);
#pragma unroll
        for (int m = 0; m < 4; ++m)
#pragma unroll
            for (int n = 0; n < 2; ++n)
                acc[m][n] = __builtin_amdgcn_mfma_i32_16x16x64_i8(a[m], b[n], acc[m][n], 0, 0, 0);
        __builtin_amdgcn_s_setprio(0);
    }

    // ---- epilogue: C/D layout col = lane&15, row = (lane>>4)*4 + reg.
    float local = 0.f;
    int lj[2];
#pragma unroll
    for (int n = 0; n < 2; ++n) lj[n] = label[col0 + wcol * 32 + n * 16 + fr];
    const int rb = kq << 2;
#pragma unroll
    for (int m = 0; m < 4; ++m) {
#pragma unroll
        for (int r = 0; r < 4; ++r) {
            const int li = label[row0 + wrow * 64 + m * 16 + rb + r];
#pragma unroll
            for (int n = 0; n < 2; ++n) {
                const float s = (float)acc[m][n][r] * DEQ;
                if (li == lj[n]) {
                    if (s < 1.0f) local += 1.0f - s;
                } else if (s > MARGIN_F) {
                    local += s;
                }
            }
        }
    }
    if (tr != tc) local *= 2.0f;   // off-diag tile stands for (i,j) and (j,i)

#pragma unroll
    for (int off = 32; off > 0; off >>= 1) local += __shfl_xor(local, off);
    if (lane == 0) red[wid] = local;
    __syncthreads();
    if (tid == 0) {
        float s = 0.f;
#pragma unroll
        for (int i = 0; i < 8; ++i) s += red[i];
        partials[t] = s;
    }
}

__global__ __launch_bounds__(256) void reduce_kernel(const float* __restrict__ partials,
                                                     float* __restrict__ out, int nb) {
    float s = 0.f;
    for (int i = threadIdx.x; i < nb; i += 256) s += partials[i];
#pragma unroll
    for (int off = 32; off > 0; off >>= 1) s += __shfl_xor(s, off);
    __shared__ float red[4];
    if ((threadIdx.x & 63) == 0) red[threadIdx.x >> 6] = s;
    __syncthreads();
    if (threadIdx.x == 0) {
        out[0] = (red[0] + red[1] + red[2] + red[3]) * (1.0f / (float)N_EMB);
        out[1] = 0.f;
        out[2] = 0.f;
    }
}

extern "C" void kernel_launch(void* const* d_in, const int* in_sizes, int n_in,
                              void* d_out, int out_size, void* d_ws, size_t ws_size,
                              hipStream_t stream) {
    const float* emb   = (const float*)d_in[0];
    const int*   label = (const int*)d_in[1];
    float*       out   = (float*)d_out;

    char*  E8      = (char*)d_ws;                                   // 4 MB
    float* partial = (float*)((char*)d_ws + (size_t)N_EMB * D_EMB); // 8.3 KB

    const int n16 = N_EMB * D_EMB / 16;
    quant_kernel<<<(n16 + 255) / 256, 256, 0, stream>>>(emb, (int4*)E8, n16);

    loss_kernel<<<NBLK, 512, 0, stream>>>(E8, label, partial);

    reduce_kernel<<<1, 256, 0, stream>>>(partial, out, NBLK);
}

// Round 20
// 42.067 us; speedup vs baseline: 1.6801x; 1.0112x over previous
//
#include <hip/hip_runtime.h>
#include <hip/hip_bf16.h>

// ContrastiveLoss: loss = ( sum_{same & sim<1} (1-sim) + sum_{diff & sim>0.5} sim ) / n
// sim = E E^T, n=8192, d=512. int8 MFMA (mfma_i32_16x16x64_i8), exact i32
// accumulation, quant scale 24, dequant 1/576.
// R20 = R19 (8 waves of 64x32, ring-3 LDS, counted vmcnt(2), one barrier per
// window, reads-before-stage, unpinned interior, T1, triangular grid) with the
// LDS swizzle corrected from (row&3) to ((row>>1)&3):
//   bank-set(fr) = 16*(fr&1) + 4*(kq^swz). swz=fr&3 covers only 4 of 8 slots
//   (fr+4 repeats) -> 4-way aliasing, measured 2.13M conflict-cycles (~34%
//   read inflation). swz=(fr>>1)&3 covers all 8 slots across fr=0..7 (only
//   fr+8 repeats) -> 2-way = free (m136).
// Applied BOTH sides (rule #21): source sw uses (tid>>3)&3 (row=tid>>2),
// read psw uses (fr>>1)&3. All fragment rows share fr's low bits, so one psw.

typedef int i32x4 __attribute__((ext_vector_type(4)));

#define N_EMB 8192
#define D_EMB 512
#define BM    128
#define HKB   64                 // K-bytes per window
#define NPH   (D_EMB / HKB)      // 8 windows
#define TILES (N_EMB / BM)       // 64
#define NBLK  (TILES * (TILES + 1) / 2)   // 2080
#define MARGIN_F 0.5f
#define QSCALE 24.0f
#define DEQ    (1.0f / (QSCALE * QSCALE))  // 1/576
#define HBYT  (BM * HKB)         // 8192 B per operand half-buffer

__device__ __forceinline__ void gll16(const void* g, void* l) {
    __builtin_amdgcn_global_load_lds(
        (const __attribute__((address_space(1))) void*)g,
        (__attribute__((address_space(3))) void*)l,
        16 /*bytes*/, 0 /*offset*/, 0 /*aux*/);
}

// fp32 -> int8 (scale 24, clamp +-127). 16 floats -> 16 bytes per thread.
__global__ __launch_bounds__(256) void quant_kernel(const float* __restrict__ in,
                                                    int4* __restrict__ out, int n16) {
    int i = blockIdx.x * blockDim.x + threadIdx.x;
    if (i >= n16) return;
    const float4* p = reinterpret_cast<const float4*>(in) + i * 4;
    int4 o;
    int* po = reinterpret_cast<int*>(&o);
#pragma unroll
    for (int j = 0; j < 4; ++j) {
        float4 v = p[j];
        int b0 = (int)rintf(fminf(fmaxf(v.x * QSCALE, -127.f), 127.f));
        int b1 = (int)rintf(fminf(fmaxf(v.y * QSCALE, -127.f), 127.f));
        int b2 = (int)rintf(fminf(fmaxf(v.z * QSCALE, -127.f), 127.f));
        int b3 = (int)rintf(fminf(fmaxf(v.w * QSCALE, -127.f), 127.f));
        po[j] = (b0 & 255) | ((b1 & 255) << 8) | ((b2 & 255) << 16) | ((b3 & 255) << 24);
    }
    out[i] = o;
}

__global__ __launch_bounds__(512) void loss_kernel(const char* __restrict__ E8,
                                                   const int* __restrict__ label,
                                                   float* __restrict__ partials) {
    // T1: XCD-contiguous logical tile index (2080 % 8 == 0)
    const int bid = blockIdx.x;
    const int t = (bid & 7) * (NBLK / 8) + (bid >> 3);

    // triangular decode: t -> (tr, tc), tr <= tc (validated R2..R19)
    int tr = (int)(64.5f - sqrtf(4160.25f - 2.0f * (float)t));
    while ((tr + 1) * TILES - ((tr + 1) * tr) / 2 <= t) ++tr;
    while (tr * TILES - (tr * (tr - 1)) / 2 > t) --tr;
    const int tc = tr + (t - (tr * TILES - (tr * (tr - 1)) / 2));

    __shared__ char  lds[3][2][HBYT];   // ring-3: [A 8KB | B 8KB] x 3 = 48 KB
    __shared__ float red[8];

    const int tid  = threadIdx.x;
    const int wid  = tid >> 6, lane = tid & 63;
    const int wrow = wid >> 2, wcol = wid & 3;   // 2x4 waves, each 64x32 out
    const int fr   = lane & 15;                  // fragment row(A)/row(B)/col(C)
    const int kq   = lane >> 4;                  // k-16B-chunk 0..3
    const int row0 = tr * BM, col0 = tc * BM;

    // staging: per half = 128 rows x 64 B = 512 x 16B slots; thread covers
    // slot tid of each operand. Phys chunk c of row r holds LOGICAL chunk
    // c ^ ((r>>1)&3): inverse swizzle on global source, lane-linear LDS dest.
    // row = tid>>2 -> (row>>1)&3 = (tid>>3)&3.
    const int sw = (((tid & 3) ^ ((tid >> 3) & 3)) << 4);
    const int r0 = tid >> 2;
    const char* gA0 = E8 + (size_t)(row0 + r0) * D_EMB + sw;
    const char* gB0 = E8 + (size_t)(col0 + r0) * D_EMB + sw;
    const int d0 = tid << 4;

    i32x4 acc[4][2] = {};

    // ds_read phys chunk: kq ^ ((row>>1)&3); fragment rows have row = X*16+fr
    // -> (row>>1)&3 = (fr>>1)&3 (16|X*16 keeps bits 1..2 of fr intact... bit1,2
    // of row come from fr since 16-multiples only add bits >=4).
    const int psw = ((kq ^ ((fr >> 1) & 3)) << 4);

    // prologue: stage windows 0 and 1 (4 glls outstanding per thread)
    gll16(gA0,       &lds[0][0][d0]); gll16(gB0,       &lds[0][1][d0]);
    gll16(gA0 + HKB, &lds[1][0][d0]); gll16(gB0 + HKB, &lds[1][1][d0]);

#pragma unroll
    for (int p = 0; p < NPH; ++p) {
        const int rg = p % 3;
        // counted wait: all but newest 2 glls done = window p landed;
        // window p+1's 2 stay in flight. Final window drains.
        if (p < NPH - 1) {
            asm volatile("s_waitcnt vmcnt(2)" ::: "memory");
        } else {
            asm volatile("s_waitcnt vmcnt(0)" ::: "memory");
        }
        __builtin_amdgcn_s_barrier();        // publish window p; ring (p+2)%3 free
        __builtin_amdgcn_sched_barrier(0);   // reads must not hoist above barrier

        // critical path first: this window's fragment reads (ordinary loads;
        // compiler emits fine-grained counted lgkmcnt before each MFMA use)
        i32x4 a[4], b[2];
#pragma unroll
        for (int m = 0; m < 4; ++m)
            a[m] = *reinterpret_cast<const i32x4*>(
                &lds[rg][0][((wrow * 64 + m * 16 + fr) << 6) + psw]);
#pragma unroll
        for (int n = 0; n < 2; ++n)
            b[n] = *reinterpret_cast<const i32x4*>(
                &lds[rg][1][((wcol * 32 + n * 16 + fr) << 6) + psw]);

        // stage window p+2 (2 windows of slack; last readers retired above)
        if (p + 2 < NPH) {
            const int rg2 = (p + 2) % 3;
            const int ko  = (p + 2) * HKB;
            gll16(gA0 + ko, &lds[rg2][0][d0]);
            gll16(gB0 + ko, &lds[rg2][1][d0]);
        }

        __builtin_amdgcn_s_setprio(1);
#pragma unroll
        for (int m = 0; m < 4; ++m)
#pragma unroll
            for (int n = 0; n < 2; ++n)
                acc[m][n] = __builtin_amdgcn_mfma_i32_16x16x64_i8(a[m], b[n], acc[m][n], 0, 0, 0);
        __builtin_amdgcn_s_setprio(0);
    }

    // ---- epilogue: C/D layout col = lane&15, row = (lane>>4)*4 + reg.
    float local = 0.f;
    int lj[2];
#pragma unroll
    for (int n = 0; n < 2; ++n) lj[n] = label[col0 + wcol * 32 + n * 16 + fr];
    const int rb = kq << 2;
#pragma unroll
    for (int m = 0; m < 4; ++m) {
#pragma unroll
        for (int r = 0; r < 4; ++r) {
            const int li = label[row0 + wrow * 64 + m * 16 + rb + r];
#pragma unroll
            for (int n = 0; n < 2; ++n) {
                const float s = (float)acc[m][n][r] * DEQ;
                if (li == lj[n]) {
                    if (s < 1.0f) local += 1.0f - s;
                } else if (s > MARGIN_F) {
                    local += s;
                }
            }
        }
    }
    if (tr != tc) local *= 2.0f;   // off-diag tile stands for (i,j) and (j,i)

#pragma unroll
    for (int off = 32; off > 0; off >>= 1) local += __shfl_xor(local, off);
    if (lane == 0) red[wid] = local;
    __syncthreads();
    if (tid == 0) {
        float s = 0.f;
#pragma unroll
        for (int i = 0; i < 8; ++i) s += red[i];
        partials[t] = s;
    }
}

__global__ __launch_bounds__(256) void reduce_kernel(const float* __restrict__ partials,
                                                     float* __restrict__ out, int nb) {
    float s = 0.f;
    for (int i = threadIdx.x; i < nb; i += 256) s += partials[i];
#pragma unroll
    for (int off = 32; off > 0; off >>= 1) s += __shfl_xor(s, off);
    __shared__ float red[4];
    if ((threadIdx.x & 63) == 0) red[threadIdx.x >> 6] = s;
    __syncthreads();
    if (threadIdx.x == 0) {
        out[0] = (red[0] + red[1] + red[2] + red[3]) * (1.0f / (float)N_EMB);
        out[1] = 0.f;
        out[2] = 0.f;
    }
}

extern "C" void kernel_launch(void* const* d_in, const int* in_sizes, int n_in,
                              void* d_out, int out_size, void* d_ws, size_t ws_size,
                              hipStream_t stream) {
    const float* emb   = (const float*)d_in[0];
    const int*   label = (const int*)d_in[1];
    float*       out   = (float*)d_out;

    char*  E8      = (char*)d_ws;                                   // 4 MB
    float* partial = (float*)((char*)d_ws + (size_t)N_EMB * D_EMB); // 8.3 KB

    const int n16 = N_EMB * D_EMB / 16;
    quant_kernel<<<(n16 + 255) / 256, 256, 0, stream>>>(emb, (int4*)E8, n16);

    loss_kernel<<<NBLK, 512, 0, stream>>>(E8, label, partial);

    reduce_kernel<<<1, 256, 0, stream>>>(partial, out, NBLK);
}